// Round 15
// baseline (1730.608 us; speedup 1.0000x reference)
//
#include <hip/hip_runtime.h>
#include <math.h>

#define TSEQ   2048
#define BATCH  2
#define DMODEL 1024
#define NLAYER 6
#define NHEAD  16
#define HDIM   64
#define DFFN   4096
#define NVOCAB 32000
#define LNEPS  1e-5f

typedef __bf16 bf16_t;
typedef bf16_t bf16x8 __attribute__((ext_vector_type(8)));
typedef float  f32x4  __attribute__((ext_vector_type(4)));
typedef unsigned short u16;
typedef u16 u16x4 __attribute__((ext_vector_type(4)));
typedef u16 u16x8 __attribute__((ext_vector_type(8)));

#define GBAR()   __builtin_amdgcn_s_barrier()
#define WLGKM0() asm volatile("s_waitcnt lgkmcnt(0)" ::: "memory")
#define WVM2()   asm volatile("s_waitcnt vmcnt(2)" ::: "memory")
#define WVM0()   asm volatile("s_waitcnt vmcnt(0)" ::: "memory")

__device__ __forceinline__ u16 f2bf(float f) {   // RNE fp32 -> bf16 bits
  unsigned u = __float_as_uint(f);
  return (u16)((u + 0x7fffu + ((u >> 16) & 1u)) >> 16);
}

__device__ __forceinline__ float exp2_raw(float x) {  // v_exp_f32: 2^x
  float r;
  asm("v_exp_f32 %0, %1" : "=v"(r) : "v"(x));
  return r;
}

__device__ __forceinline__ void gload16(const void* g, void* l) {
  __builtin_amdgcn_global_load_lds(
      (const __attribute__((address_space(1))) unsigned int*)g,
      (__attribute__((address_space(3))) unsigned int*)l, 16, 0, 0);
}

// ----------------------------- embedding ---------------------------------
__global__ __launch_bounds__(256) void embed_kernel(
    const int* __restrict__ ids, const float* __restrict__ emb,
    const float* __restrict__ pos, float* __restrict__ x) {
  int bt  = blockIdx.x;
  int t   = bt & (TSEQ - 1);
  int id  = ids[bt];
  int tid = threadIdx.x;
  float4 e = ((const float4*)(emb + (size_t)id * DMODEL))[tid];
  float4 p = ((const float4*)(pos + (size_t)t  * DMODEL))[tid];
  float4 r;
  r.x = e.x + p.x; r.y = e.y + p.y; r.z = e.z + p.z; r.w = e.w + p.w;
  ((float4*)(x + (size_t)bt * DMODEL))[tid] = r;
}

// ------------------------- layernorm body (bf16 out) ----------------------
__device__ __forceinline__ void ln_body(
    const float* __restrict__ x, const float* __restrict__ g,
    const float* __restrict__ b, u16* __restrict__ y, int row, float* red) {
  int tid = threadIdx.x;
  int lane = tid & 63, w = tid >> 6;
  float4 v = ((const float4*)(x + (size_t)row * DMODEL))[tid];
  float s = v.x + v.y + v.z + v.w;
#pragma unroll
  for (int o = 32; o >= 1; o >>= 1) s += __shfl_xor(s, o);
  if (lane == 0) red[w] = s;
  __syncthreads();
  float mu = (red[0] + red[1] + red[2] + red[3]) * (1.0f / DMODEL);
  float d0 = v.x - mu, d1 = v.y - mu, d2 = v.z - mu, d3 = v.w - mu;
  float s2 = d0*d0 + d1*d1 + d2*d2 + d3*d3;
#pragma unroll
  for (int o = 32; o >= 1; o >>= 1) s2 += __shfl_xor(s2, o);
  if (lane == 0) red[4 + w] = s2;
  __syncthreads();
  float var = (red[4] + red[5] + red[6] + red[7]) * (1.0f / DMODEL);
  float rs = rsqrtf(var + LNEPS);
  float4 gv = ((const float4*)g)[tid];
  float4 bv = ((const float4*)b)[tid];
  u16x4 r;
  r[0] = f2bf(d0 * rs * gv.x + bv.x);
  r[1] = f2bf(d1 * rs * gv.y + bv.y);
  r[2] = f2bf(d2 * rs * gv.z + bv.z);
  r[3] = f2bf(d3 * rs * gv.w + bv.w);
  ((u16x4*)(y + (size_t)row * DMODEL))[tid] = r;
}

__global__ __launch_bounds__(256) void ln_kernel(
    const float* __restrict__ x, const float* __restrict__ g,
    const float* __restrict__ b, u16* __restrict__ y) {
  __shared__ float red[8];
  ln_body(x, g, b, y, blockIdx.x, red);
}

__device__ __forceinline__ void cvt8_body(const float* src, u16* dst, size_t i) {
  f32x4 a = __builtin_nontemporal_load((const f32x4*)(src + i));
  f32x4 b = __builtin_nontemporal_load((const f32x4*)(src + i) + 1);
  u16x8 r;
  r[0] = f2bf(a[0]); r[1] = f2bf(a[1]); r[2] = f2bf(a[2]); r[3] = f2bf(a[3]);
  r[4] = f2bf(b[0]); r[5] = f2bf(b[1]); r[6] = f2bf(b[2]); r[7] = f2bf(b[3]);
  *(u16x8*)(dst + i) = r;
}

// per-layer prep: cvt of 4 weight mats (blocks 0..6143) + ln1 (6144..10239)
__global__ __launch_bounds__(256) void prep_kernel(
    const float* __restrict__ s0, const float* __restrict__ s1,
    const float* __restrict__ s2, const float* __restrict__ s3,
    u16* __restrict__ d0, u16* __restrict__ d1,
    u16* __restrict__ d2, u16* __restrict__ d3,
    const float* __restrict__ x, const float* __restrict__ g,
    const float* __restrict__ b, u16* __restrict__ y) {
  __shared__ float red[8];
  int bid = blockIdx.x;
  if (bid >= 6144) {
    ln_body(x, g, b, y, bid - 6144, red);
    return;
  }
  const float* src; u16* dst; int idx;
  if (bid < 1536)      { src = s0; dst = d0; idx = bid; }
  else if (bid < 2048) { src = s1; dst = d1; idx = bid - 1536; }
  else if (bid < 4096) { src = s2; dst = d2; idx = bid - 2048; }
  else                 { src = s3; dst = d3; idx = bid - 4096; }
  cvt8_body(src, dst, ((size_t)idx * 256 + threadIdx.x) * 8);
}

// final prep: lnf (blocks 0..4095) + embedding cvt (4096..20095)
__global__ __launch_bounds__(256) void finprep_kernel(
    const float* __restrict__ x, const float* __restrict__ g,
    const float* __restrict__ b, u16* __restrict__ y,
    const float* __restrict__ emb, u16* __restrict__ embb) {
  __shared__ float red[8];
  int bid = blockIdx.x;
  if (bid < 4096) {
    ln_body(x, g, b, y, bid, red);
    return;
  }
  cvt8_body(emb, embb, ((size_t)(bid - 4096) * 256 + threadIdx.x) * 8);
}

__device__ __forceinline__ float gelu_f(float v) {
  return 0.5f * v * (1.0f + erff(v * 0.70710678118654752f));
}

// ------------------------- shared LDS-read helpers -------------------------
__device__ __forceinline__ bf16x8 ldsrd(const char* p) {
  return *(const bf16x8*)p;
}

// =============== 128x128 8-phase MFMA GEMM (all GEMMs) =====================
template<int PH>
__device__ __forceinline__ void rd_a2(bf16x8 (&afr)[2][2], const char* base,
                                      int aB0, int aB1) {
  afr[0][0] = ldsrd(base + aB0 + PH * 4096);
  afr[0][1] = ldsrd(base + aB1 + PH * 4096);
  afr[1][0] = ldsrd(base + aB0 + PH * 4096 + 2048);
  afr[1][1] = ldsrd(base + aB1 + PH * 4096 + 2048);
}

__device__ __forceinline__ void rd_b2(bf16x8 (&bfr)[2][2], const char* base,
                                      int bB0, int bB1) {
#pragma unroll
  for (int ni = 0; ni < 2; ++ni) {
    bfr[ni][0] = ldsrd(base + bB0 + ni * 2048);
    bfr[ni][1] = ldsrd(base + bB1 + ni * 2048);
  }
}

template<int PH>
__device__ __forceinline__ void mm8(f32x4 (&acc)[4][2], bf16x8 (&afr)[2][2],
                                    bf16x8 (&bfr)[2][2]) {
#pragma unroll
  for (int ni = 0; ni < 2; ++ni) {
    acc[PH*2+0][ni] = __builtin_amdgcn_mfma_f32_16x16x32_bf16(bfr[ni][0], afr[0][0], acc[PH*2+0][ni], 0, 0, 0);
    acc[PH*2+0][ni] = __builtin_amdgcn_mfma_f32_16x16x32_bf16(bfr[ni][1], afr[0][1], acc[PH*2+0][ni], 0, 0, 0);
    acc[PH*2+1][ni] = __builtin_amdgcn_mfma_f32_16x16x32_bf16(bfr[ni][0], afr[1][0], acc[PH*2+1][ni], 0, 0, 0);
    acc[PH*2+1][ni] = __builtin_amdgcn_mfma_f32_16x16x32_bf16(bfr[ni][1], afr[1][1], acc[PH*2+1][ni], 0, 0, 0);
  }
}

template<int ACT, bool BIAS, bool RES, bool OUTBF>
__global__ __launch_bounds__(512, 4) void gemm128_8ph(
    const bf16_t* __restrict__ A, const bf16_t* __restrict__ W,
    const float* __restrict__ bias, const float* __restrict__ res,
    void* __restrict__ Cout, int M, int N, int K) {
  __shared__ char lds[65536];
  char* Asc = lds;
  char* Bsc = lds + 32768;

  const int tid  = threadIdx.x;
  const int lane = tid & 63;
  const int w    = tid >> 6;
  const int wr   = w >> 2, wc = w & 3;

  const int nwg = gridDim.x * gridDim.y;
  const int bid = blockIdx.y * gridDim.x + blockIdx.x;
  const int swz = (bid & 7) * (nwg >> 3) + (bid >> 3);
  const int m0 = (swz & 31) << 7;
  const int n0 = (swz >> 5) << 7;

  const size_t K2 = (size_t)K * 2;
  const int KT = K >> 6;

  const int qsrc = (((tid & 7) ^ ((tid >> 3) & 7)) << 4);
  const char* srcA = (const char*)A + (size_t)(m0 + (tid >> 3)) * K2 + qsrc;
  const char* srcB = (const char*)W + (size_t)(n0 + (tid >> 3)) * K2 + qsrc;
  char* dstA = Asc + (tid & 448) * 16;
  char* dstB = Bsc + (tid & 448) * 16;

  auto STG = [&](int kt, int part) {
    if (kt >= KT) return;
    const int h = part & 1;
    const size_t so = (size_t)(h * 64) * K2 + (size_t)kt * 128;
    const int dofs = ((kt & 1) << 14) + (h << 13);
    if (part >= 2) gload16(srcA + so, dstA + dofs);
    else           gload16(srcB + so, dstB + dofs);
  };

  const int rr = lane & 15;
  const int q0 = (((lane >> 4) ^ (lane & 7)) << 4);
  const int aB0 = ((wr << 6) + rr) * 128 + q0;
  const int aB1 = ((wr << 6) + rr) * 128 + (q0 ^ 64);
  const int bB0 = ((wc << 5) + rr) * 128 + q0;
  const int bB1 = ((wc << 5) + rr) * 128 + (q0 ^ 64);

  bf16x8 bfr[2][2];
  bf16x8 afr[2][2];
  f32x4 acc[4][2] = {};

  STG(0, 0); STG(0, 1); STG(0, 2); STG(0, 3);
  STG(1, 0); STG(1, 1);
  WVM2();
  GBAR();

  const int iters = KT >> 1;
  for (int t = 0; t < iters; ++t) {
    const int d = t << 1;
    rd_b2(bfr, Bsc, bB0, bB1);
    rd_a2<0>(afr, Asc, aB0, aB1);
    STG(d + 1, 2); STG(d + 1, 3);
    GBAR(); WLGKM0();
    __builtin_amdgcn_s_setprio(1); mm8<0>(acc, afr, bfr); __builtin_amdgcn_s_setprio(0);
    GBAR();
    rd_a2<1>(afr, Asc, aB0, aB1);
    STG(d + 2, 0); STG(d + 2, 1);
    GBAR(); WLGKM0();
    __builtin_amdgcn_s_setprio(1); mm8<1>(acc, afr, bfr); __builtin_amdgcn_s_setprio(0);
    if (t == iters - 1) { WVM0(); } else { WVM2(); }
    GBAR();
    rd_b2(bfr, Bsc + 16384, bB0, bB1);
    rd_a2<0>(afr, Asc + 16384, aB0, aB1);
    STG(d + 2, 2); STG(d + 2, 3);
    GBAR(); WLGKM0();
    __builtin_amdgcn_s_setprio(1); mm8<0>(acc, afr, bfr); __builtin_amdgcn_s_setprio(0);
    GBAR();
    rd_a2<1>(afr, Asc + 16384, aB0, aB1);
    STG(d + 3, 0); STG(d + 3, 1);
    GBAR(); WLGKM0();
    __builtin_amdgcn_s_setprio(1); mm8<1>(acc, afr, bfr); __builtin_amdgcn_s_setprio(0);
    WVM2();
    GBAR();
  }

  const int cc = lane & 15;
  const int jb = (lane >> 4) << 2;
  const int orow0 = m0 + wr * 64;
  const int ocol0 = n0 + wc * 32;
#pragma unroll
  for (int mi = 0; mi < 4; ++mi) {
    const int row = orow0 + mi * 16 + cc;
#pragma unroll
    for (int ni = 0; ni < 2; ++ni) {
      const int col = ocol0 + ni * 16 + jb;
      f32x4 v = acc[mi][ni];
      if (BIAS) v += *(const f32x4*)(bias + col);
      if (ACT == 1) {
#pragma unroll
        for (int j = 0; j < 4; ++j) v[j] = gelu_f(v[j]);
      }
      if (RES) v += *(const f32x4*)(res + (size_t)row * N + col);
      if (OUTBF) {
        u16x4 r;
#pragma unroll
        for (int j = 0; j < 4; ++j) r[j] = f2bf(v[j]);
        *(u16x4*)((u16*)Cout + (size_t)row * N + col) = r;
      } else {
        *(f32x4*)((float*)Cout + (size_t)row * N + col) = v;
      }
    }
  }
}

// ----------------- MFMA flash attention (QBLK=128, KVBLK=128) --------------
__global__ __launch_bounds__(512) void attn_mfma_kernel(
    const u16* __restrict__ qkv, u16* __restrict__ out) {
  const int bh  = blockIdx.y;
  const int b = bh >> 4, h = bh & 15;
  const int tid = threadIdx.x;
  const int lane = tid & 63, w = tid >> 6;

  __shared__ u16 Ks[128][72];
  __shared__ u16 Vt[64][136];
  __shared__ u16 Ps[8][16][136];

  const size_t rowstr = 3 * DMODEL;
  const u16* base = qkv + (size_t)b * TSEQ * rowstr;

  const int fr = lane & 15;
  const int fk = (lane >> 4) * 8;

  bf16x8 onesf;
#pragma unroll
  for (int i = 0; i < 8; ++i) ((u16*)&onesf)[i] = 0x3F80;  // bf16 1.0

  const int skr = tid >> 2;
  const int skc = (tid & 3) * 16;
  const int vk0 = (tid & 63) * 2;
  const int vd0 = (tid >> 6) * 8;

#pragma unroll 1
  for (int half = 0; half < 2; ++half) {
    const int st  = half ? (15 - (int)blockIdx.x) : (int)blockIdx.x;
    const int qb0 = st * 128;
    const int qminw = qb0 + w * 16;
    const int qrow = qminw + fr;

    u16x8 q0r = *(const u16x8*)(base + (size_t)qrow * rowstr + h * HDIM + fk);
    u16x8 q1r = *(const u16x8*)(base + (size_t)qrow * rowstr + h * HDIM + fk + 32);
    bf16x8 qf0, qf1;
#pragma unroll
    for (int i = 0; i < 8; ++i) {
      ((u16*)&qf0)[i] = f2bf(__uint_as_float((unsigned)q0r[i] << 16) * 0.18033688011112042f);
      ((u16*)&qf1)[i] = f2bf(__uint_as_float((unsigned)q1r[i] << 16) * 0.18033688011112042f);
    }

    f32x4 o[4] = {};
    f32x4 ls = {};

    u16x8 k0, k1, va0, vb0;
    {
      const u16* kr = base + (size_t)skr * rowstr + DMODEL + h * HDIM + skc;
      k0 = *(const u16x8*)kr;  k1 = *(const u16x8*)(kr + 8);
      const u16* vr = base + (size_t)vk0 * rowstr + 2 * DMODEL + h * HDIM + vd0;
      va0 = *(const u16x8*)vr; vb0 = *(const u16x8*)(vr + rowstr);
    }

    for (int s0 = 0; s0 < qb0 + 128; s0 += 128) {
      __syncthreads();
      *(u16x8*)&Ks[skr][skc]     = k0;
      *(u16x8*)&Ks[skr][skc + 8] = k1;
#pragma unroll
      for (int i = 0; i < 8; ++i)
        *(unsigned*)&Vt[vd0 + i][vk0] = (unsigned)va0[i] | ((unsigned)vb0[i] << 16);
      __syncthreads();

      if (s0 + 128 < qb0 + 128) {
        const u16* kr = base + (size_t)(s0 + 128 + skr) * rowstr + DMODEL + h * HDIM + skc;
        k0 = *(const u16x8*)kr;  k1 = *(const u16x8*)(kr + 8);
        const u16* vr = base + (size_t)(s0 + 128 + vk0) * rowstr + 2 * DMODEL + h * HDIM + vd0;
        va0 = *(const u16x8*)vr; vb0 = *(const u16x8*)(vr + rowstr);
      } else if (half == 0) {
        const u16* kr = base + (size_t)skr * rowstr + DMODEL + h * HDIM + skc;
        k0 = *(const u16x8*)kr;  k1 = *(const u16x8*)(kr + 8);
        const u16* vr = base + (size_t)vk0 * rowstr + 2 * DMODEL + h * HDIM + vd0;
        va0 = *(const u16x8*)vr; vb0 = *(const u16x8*)(vr + rowstr);
      }

      f32x4 s[8];
      __builtin_amdgcn_s_setprio(1);
#pragma unroll
      for (int ni = 0; ni < 8; ++ni) {
        f32x4 t = {};
        bf16x8 kf0 = *(const bf16x8*)&Ks[ni * 16 + fr][fk];
        bf16x8 kf1 = *(const bf16x8*)&Ks[ni * 16 + fr][fk + 32];
        t = __builtin_amdgcn_mfma_f32_16x16x32_bf16(qf0, kf0, t, 0, 0, 0);
        t = __builtin_amdgcn_mfma_f32_16x16x32_bf16(qf1, kf1, t, 0, 0, 0);
        s[ni] = t;
      }
      __builtin_amdgcn_s_setprio(0);

      if (s0 == qb0) {
        const int q0_ = qminw + (lane >> 4) * 4;
#pragma unroll
        for (int ni = 0; ni < 8; ++ni)
#pragma unroll
          for (int j = 0; j < 4; ++j)
            if (s0 + ni * 16 + fr > q0_ + j) s[ni][j] = -3e38f;
      }

#pragma unroll
      for (int ni = 0; ni < 8; ++ni)
#pragma unroll
        for (int j = 0; j < 4; ++j) {
          float pv = exp2_raw(fminf(s[ni][j], 115.41560327f) - 11.541560327111707f);
          Ps[w][(lane >> 4) * 4 + j][ni * 16 + fr] = f2bf(pv);
        }
      WLGKM0();

      bf16x8 pf0 = *(const bf16x8*)&Ps[w][fr][fk];
      bf16x8 pf1 = *(const bf16x8*)&Ps[w][fr][fk + 32];
      bf16x8 pf2 = *(const bf16x8*)&Ps[w][fr][64 + fk];
      bf16x8 pf3 = *(const bf16x8*)&Ps[w][fr][96 + fk];
      __builtin_amdgcn_s_setprio(1);
#pragma unroll
      for (int ni = 0; ni < 4; ++ni) {
        bf16x8 vf0 = *(const bf16x8*)&Vt[ni * 16 + fr][fk];
        bf16x8 vf1 = *(const bf16x8*)&Vt[ni * 16 + fr][fk + 32];
        bf16x8 vf2 = *(const bf16x8*)&Vt[ni * 16 + fr][64 + fk];
        bf16x8 vf3 = *(const bf16x8*)&Vt[ni * 16 + fr][96 + fk];
        o[ni] = __builtin_amdgcn_mfma_f32_16x16x32_bf16(pf0, vf0, o[ni], 0, 0, 0);
        o[ni] = __builtin_amdgcn_mfma_f32_16x16x32_bf16(pf1, vf1, o[ni], 0, 0, 0);
        o[ni] = __builtin_amdgcn_mfma_f32_16x16x32_bf16(pf2, vf2, o[ni], 0, 0, 0);
        o[ni] = __builtin_amdgcn_mfma_f32_16x16x32_bf16(pf3, vf3, o[ni], 0, 0, 0);
      }
      ls = __builtin_amdgcn_mfma_f32_16x16x32_bf16(pf0, onesf, ls, 0, 0, 0);
      ls = __builtin_amdgcn_mfma_f32_16x16x32_bf16(pf1, onesf, ls, 0, 0, 0);
      ls = __builtin_amdgcn_mfma_f32_16x16x32_bf16(pf2, onesf, ls, 0, 0, 0);
      ls = __builtin_amdgcn_mfma_f32_16x16x32_bf16(pf3, onesf, ls, 0, 0, 0);
      __builtin_amdgcn_s_setprio(0);
    }

#pragma unroll
    for (int j = 0; j < 4; ++j) {
      float inv = 1.0f / ls[j];
      int q = qminw + (lane >> 4) * 4 + j;
      u16* op = out + ((size_t)(b * TSEQ) + q) * DMODEL + h * HDIM + fr;
#pragma unroll
      for (int ni = 0; ni < 4; ++ni)
        op[ni * 16] = f2bf(o[ni][j] * inv);
    }
  }
}

// ------------------------------ launcher ----------------------------------
extern "C" void kernel_launch(void* const* d_in, const int* in_sizes, int n_in,
                              void* d_out, int out_size, void* d_ws, size_t ws_size,
                              hipStream_t stream) {
  const int*   ids    = (const int*)d_in[0];
  const float* emb    = (const float*)d_in[1];
  const float* pos    = (const float*)d_in[2];
  const float* ln1_g  = (const float*)d_in[3];
  const float* ln1_b  = (const float*)d_in[4];
  const float* ln2_g  = (const float*)d_in[5];
  const float* ln2_b  = (const float*)d_in[6];
  const float* qkv_w  = (const float*)d_in[7];
  const float* out_w  = (const float*)d_in[8];
  const float* mlp_w1 = (const float*)d_in[9];
  const float* mlp_b1 = (const float*)d_in[10];
  const float* mlp_w2 = (const float*)d_in[11];
  const float* mlp_b2 = (const float*)d_in[12];
  const float* lnf_g  = (const float*)d_in[13];
  const float* lnf_b  = (const float*)d_in[14];
  float* outp = (float*)d_out;

  const int M = BATCH * TSEQ;                         // 4096
  char* p = (char*)d_ws;
  float* x    = (float*)p;  p += (size_t)M * DMODEL * 4;
  u16*   yb   = (u16*)p;    p += (size_t)M * DMODEL * 2;
  u16*   qkvb = (u16*)p;    p += (size_t)M * 3 * DMODEL * 2;
  u16*   mid  = (u16*)p;    p += (size_t)M * DFFN * 2;
  u16*   wq   = (u16*)p;    p += (size_t)3 * DMODEL * DMODEL * 2;
  u16*   wo   = (u16*)p;    p += (size_t)DMODEL * DMODEL * 2;
  u16*   w1   = (u16*)p;    p += (size_t)DFFN * DMODEL * 2;
  u16*   w2   = (u16*)p;    p += (size_t)DMODEL * DFFN * 2;
  u16*   embb = qkvb;  // final stage: reuse qkvb+mid+wq/wo (all dead)

  embed_kernel<<<M, 256, 0, stream>>>(ids, emb, pos, x);

  for (int l = 0; l < NLAYER; ++l) {
    prep_kernel<<<10240, 256, 0, stream>>>(
        qkv_w  + (size_t)l * 3 * DMODEL * DMODEL,
        out_w  + (size_t)l * DMODEL * DMODEL,
        mlp_w1 + (size_t)l * DFFN * DMODEL,
        mlp_w2 + (size_t)l * DMODEL * DFFN,
        wq, wo, w1, w2,
        x, ln1_g + l * DMODEL, ln1_b + l * DMODEL, yb);

    gemm128_8ph<0, false, false, true><<<dim3(3 * DMODEL / 128, M / 128), 512, 0, stream>>>(
        (const bf16_t*)yb, (const bf16_t*)wq, nullptr, nullptr, qkvb, M, 3 * DMODEL, DMODEL);
    attn_mfma_kernel<<<dim3(8, BATCH * NHEAD), 512, 0, stream>>>(qkvb, yb);
    gemm128_8ph<0, false, true, false><<<dim3(DMODEL / 128, M / 128), 512, 0, stream>>>(
        (const bf16_t*)yb, (const bf16_t*)wo, nullptr, x, x, M, DMODEL, DMODEL);
    ln_kernel<<<M, 256, 0, stream>>>(x, ln2_g + l * DMODEL, ln2_b + l * DMODEL, yb);
    gemm128_8ph<1, true, false, true><<<dim3(DFFN / 128, M / 128), 512, 0, stream>>>(
        (const bf16_t*)yb, (const bf16_t*)w1, mlp_b1 + (size_t)l * DFFN, nullptr, mid,
        M, DFFN, DMODEL);
    gemm128_8ph<0, true, true, false><<<dim3(DMODEL / 128, M / 128), 512, 0, stream>>>(
        (const bf16_t*)mid, (const bf16_t*)w2, mlp_b2 + (size_t)l * DMODEL, x, x,
        M, DMODEL, DFFN);
  }

  finprep_kernel<<<20096, 256, 0, stream>>>(x, lnf_g, lnf_b, yb, emb, embb);
  gemm128_8ph<0, false, false, false><<<dim3(NVOCAB / 128, M / 128), 512, 0, stream>>>(
      (const bf16_t*)yb, (const bf16_t*)embb, nullptr, nullptr, outp, M, NVOCAB, DMODEL);
}

// Round 16
// 1600.818 us; speedup vs baseline: 1.0811x; 1.0811x over previous
//
#include <hip/hip_runtime.h>
#include <math.h>

#define TSEQ   2048
#define BATCH  2
#define DMODEL 1024
#define NLAYER 6
#define NHEAD  16
#define HDIM   64
#define DFFN   4096
#define NVOCAB 32000
#define LNEPS  1e-5f

typedef __bf16 bf16_t;
typedef bf16_t bf16x8 __attribute__((ext_vector_type(8)));
typedef float  f32x4  __attribute__((ext_vector_type(4)));
typedef unsigned short u16;
typedef u16 u16x4 __attribute__((ext_vector_type(4)));
typedef u16 u16x8 __attribute__((ext_vector_type(8)));

#define GBAR()   __builtin_amdgcn_s_barrier()
#define WLGKM0() asm volatile("s_waitcnt lgkmcnt(0)" ::: "memory")
#define WVM4()   asm volatile("s_waitcnt vmcnt(4)" ::: "memory")
#define WVM2()   asm volatile("s_waitcnt vmcnt(2)" ::: "memory")
#define WVM0()   asm volatile("s_waitcnt vmcnt(0)" ::: "memory")

__device__ __forceinline__ u16 f2bf(float f) {   // RNE fp32 -> bf16 bits
  unsigned u = __float_as_uint(f);
  return (u16)((u + 0x7fffu + ((u >> 16) & 1u)) >> 16);
}

__device__ __forceinline__ float exp2_raw(float x) {  // v_exp_f32: 2^x
  float r;
  asm("v_exp_f32 %0, %1" : "=v"(r) : "v"(x));
  return r;
}

__device__ __forceinline__ void gload16(const void* g, void* l) {
  __builtin_amdgcn_global_load_lds(
      (const __attribute__((address_space(1))) unsigned int*)g,
      (__attribute__((address_space(3))) unsigned int*)l, 16, 0, 0);
}

// ----------------------------- embedding ---------------------------------
__global__ __launch_bounds__(256) void embed_kernel(
    const int* __restrict__ ids, const float* __restrict__ emb,
    const float* __restrict__ pos, float* __restrict__ x) {
  int bt  = blockIdx.x;
  int t   = bt & (TSEQ - 1);
  int id  = ids[bt];
  int tid = threadIdx.x;
  float4 e = ((const float4*)(emb + (size_t)id * DMODEL))[tid];
  float4 p = ((const float4*)(pos + (size_t)t  * DMODEL))[tid];
  float4 r;
  r.x = e.x + p.x; r.y = e.y + p.y; r.z = e.z + p.z; r.w = e.w + p.w;
  ((float4*)(x + (size_t)bt * DMODEL))[tid] = r;
}

// ------------------------- layernorm body (bf16 out) ----------------------
__device__ __forceinline__ void ln_body(
    const float* __restrict__ x, const float* __restrict__ g,
    const float* __restrict__ b, u16* __restrict__ y, int row, float* red) {
  int tid = threadIdx.x;
  int lane = tid & 63, w = tid >> 6;
  float4 v = ((const float4*)(x + (size_t)row * DMODEL))[tid];
  float s = v.x + v.y + v.z + v.w;
#pragma unroll
  for (int o = 32; o >= 1; o >>= 1) s += __shfl_xor(s, o);
  if (lane == 0) red[w] = s;
  __syncthreads();
  float mu = (red[0] + red[1] + red[2] + red[3]) * (1.0f / DMODEL);
  float d0 = v.x - mu, d1 = v.y - mu, d2 = v.z - mu, d3 = v.w - mu;
  float s2 = d0*d0 + d1*d1 + d2*d2 + d3*d3;
#pragma unroll
  for (int o = 32; o >= 1; o >>= 1) s2 += __shfl_xor(s2, o);
  if (lane == 0) red[4 + w] = s2;
  __syncthreads();
  float var = (red[4] + red[5] + red[6] + red[7]) * (1.0f / DMODEL);
  float rs = rsqrtf(var + LNEPS);
  float4 gv = ((const float4*)g)[tid];
  float4 bv = ((const float4*)b)[tid];
  u16x4 r;
  r[0] = f2bf(d0 * rs * gv.x + bv.x);
  r[1] = f2bf(d1 * rs * gv.y + bv.y);
  r[2] = f2bf(d2 * rs * gv.z + bv.z);
  r[3] = f2bf(d3 * rs * gv.w + bv.w);
  ((u16x4*)(y + (size_t)row * DMODEL))[tid] = r;
}

__global__ __launch_bounds__(256) void ln_kernel(
    const float* __restrict__ x, const float* __restrict__ g,
    const float* __restrict__ b, u16* __restrict__ y) {
  __shared__ float red[8];
  ln_body(x, g, b, y, blockIdx.x, red);
}

__device__ __forceinline__ void cvt8_body(const float* src, u16* dst, size_t i) {
  f32x4 a = __builtin_nontemporal_load((const f32x4*)(src + i));
  f32x4 b = __builtin_nontemporal_load((const f32x4*)(src + i) + 1);
  u16x8 r;
  r[0] = f2bf(a[0]); r[1] = f2bf(a[1]); r[2] = f2bf(a[2]); r[3] = f2bf(a[3]);
  r[4] = f2bf(b[0]); r[5] = f2bf(b[1]); r[6] = f2bf(b[2]); r[7] = f2bf(b[3]);
  *(u16x8*)(dst + i) = r;
}

// per-layer prep: cvt of 4 weight mats (blocks 0..6143) + ln1 (6144..10239)
__global__ __launch_bounds__(256) void prep_kernel(
    const float* __restrict__ s0, const float* __restrict__ s1,
    const float* __restrict__ s2, const float* __restrict__ s3,
    u16* __restrict__ d0, u16* __restrict__ d1,
    u16* __restrict__ d2, u16* __restrict__ d3,
    const float* __restrict__ x, const float* __restrict__ g,
    const float* __restrict__ b, u16* __restrict__ y) {
  __shared__ float red[8];
  int bid = blockIdx.x;
  if (bid >= 6144) {
    ln_body(x, g, b, y, bid - 6144, red);
    return;
  }
  const float* src; u16* dst; int idx;
  if (bid < 1536)      { src = s0; dst = d0; idx = bid; }
  else if (bid < 2048) { src = s1; dst = d1; idx = bid - 1536; }
  else if (bid < 4096) { src = s2; dst = d2; idx = bid - 2048; }
  else                 { src = s3; dst = d3; idx = bid - 4096; }
  cvt8_body(src, dst, ((size_t)idx * 256 + threadIdx.x) * 8);
}

// final prep: lnf (blocks 0..4095) + embedding cvt (4096..20095)
__global__ __launch_bounds__(256) void finprep_kernel(
    const float* __restrict__ x, const float* __restrict__ g,
    const float* __restrict__ b, u16* __restrict__ y,
    const float* __restrict__ emb, u16* __restrict__ embb) {
  __shared__ float red[8];
  int bid = blockIdx.x;
  if (bid < 4096) {
    ln_body(x, g, b, y, bid, red);
    return;
  }
  cvt8_body(emb, embb, ((size_t)(bid - 4096) * 256 + threadIdx.x) * 8);
}

__device__ __forceinline__ float gelu_f(float v) {
  return 0.5f * v * (1.0f + erff(v * 0.70710678118654752f));
}

// ------------------------- shared LDS-read helpers -------------------------
__device__ __forceinline__ bf16x8 ldsrd(const char* p) {
  return *(const bf16x8*)p;
}

// =============== 256x256 8-phase MFMA GEMM (logits) ========================
template<int QD>
__device__ __forceinline__ void rd_a(bf16x8 (&afr)[2][2], const char* base,
                                     int aB0, int aB1) {
  afr[0][0] = ldsrd(base + aB0 + QD * 4096);
  afr[0][1] = ldsrd(base + aB1 + QD * 4096);
  afr[1][0] = ldsrd(base + aB0 + QD * 4096 + 2048);
  afr[1][1] = ldsrd(base + aB1 + QD * 4096 + 2048);
}

__device__ __forceinline__ void rd_b(bf16x8 (&bfr)[4][2], const char* base,
                                     int bB0, int bB1) {
#pragma unroll
  for (int ni = 0; ni < 4; ++ni) {
    bfr[ni][0] = ldsrd(base + bB0 + ni * 2048);
    bfr[ni][1] = ldsrd(base + bB1 + ni * 2048);
  }
}

// Transposed-C: mfma(B-frag, A-frag) -> lane j-index = consecutive N-cols.
template<int QD>
__device__ __forceinline__ void mm16(f32x4 (&acc)[8][4], bf16x8 (&afr)[2][2],
                                     bf16x8 (&bfr)[4][2]) {
#pragma unroll
  for (int ni = 0; ni < 4; ++ni) {
    acc[QD*2+0][ni] = __builtin_amdgcn_mfma_f32_16x16x32_bf16(bfr[ni][0], afr[0][0], acc[QD*2+0][ni], 0, 0, 0);
    acc[QD*2+0][ni] = __builtin_amdgcn_mfma_f32_16x16x32_bf16(bfr[ni][1], afr[0][1], acc[QD*2+0][ni], 0, 0, 0);
    acc[QD*2+1][ni] = __builtin_amdgcn_mfma_f32_16x16x32_bf16(bfr[ni][0], afr[1][0], acc[QD*2+1][ni], 0, 0, 0);
    acc[QD*2+1][ni] = __builtin_amdgcn_mfma_f32_16x16x32_bf16(bfr[ni][1], afr[1][1], acc[QD*2+1][ni], 0, 0, 0);
  }
}

// NTB: fp32-out LDS-bounce epilogue with wave-contiguous 1KB NT stores.
// m-fast XCD chunk walk (R12/R14 config — best measured for logits).
template<int ACT, bool BIAS, bool OUTBF, bool NTB>
__global__ __launch_bounds__(512, 2) void gemm_mfma256(
    const bf16_t* __restrict__ A, const bf16_t* __restrict__ W,
    const float* __restrict__ bias, void* __restrict__ Cout,
    int M, int N, int K) {
  __shared__ char lds[131072];
  char* Asc = lds;
  char* Bsc = lds + 65536;

  const int tid  = threadIdx.x;
  const int lane = tid & 63;
  const int w    = tid >> 6;
  const int wr   = w >> 2, wc = w & 3;

  const int nwg = gridDim.x * gridDim.y;
  const int bid = blockIdx.y * gridDim.x + blockIdx.x;
  const int swz = (bid & 7) * (nwg >> 3) + (bid >> 3);
  const int m0 = (swz & 15) << 8;
  const int n0 = (swz >> 4) << 8;

  const size_t K2 = (size_t)K * 2;
  const int KT = K >> 6;

  const int qsrc = (((tid & 7) ^ ((tid >> 3) & 7)) << 4);
  const char* srcA = (const char*)A + (size_t)(m0 + (tid >> 3)) * K2 + qsrc;
  const char* srcB = (const char*)W + (size_t)(n0 + (tid >> 3)) * K2 + qsrc;
  char* dstA = Asc + (tid & 448) * 16;
  char* dstB = Bsc + (tid & 448) * 16;

  auto STG = [&](int kt, int part) {
    if (kt >= KT) return;
    const int h = part & 1;
    const size_t so = (size_t)(h * 128) * K2 + (size_t)kt * 128;
    const int dofs = ((kt & 1) << 15) + (h << 14);
    if (part >= 2) {
      gload16(srcA + so, dstA + dofs);
      gload16(srcA + so + 64 * K2, dstA + dofs + 8192);
    } else {
      gload16(srcB + so, dstB + dofs);
      gload16(srcB + so + 64 * K2, dstB + dofs + 8192);
    }
  };

  const int rr = lane & 15;
  const int q0 = (((lane >> 4) ^ (lane & 7)) << 4);
  const int aB0 = ((wr << 7) + rr) * 128 + q0;
  const int aB1 = ((wr << 7) + rr) * 128 + (q0 ^ 64);
  const int bB0 = ((wc << 6) + rr) * 128 + q0;
  const int bB1 = ((wc << 6) + rr) * 128 + (q0 ^ 64);

  bf16x8 bfr[4][2];
  bf16x8 afr[2][2];
  f32x4 acc[8][4] = {};

  STG(0, 0); STG(0, 1); STG(0, 2); STG(0, 3);
  STG(1, 0); STG(1, 1);
  WVM4();
  GBAR();

  const int iters = KT >> 1;
  for (int t = 0; t < iters; ++t) {
    const int d = t << 1;
    rd_b(bfr, Bsc, bB0, bB1);
    rd_a<0>(afr, Asc, aB0, aB1);
    STG(d + 1, 2); STG(d + 1, 3);
    GBAR(); WLGKM0();
    __builtin_amdgcn_s_setprio(1); mm16<0>(acc, afr, bfr); __builtin_amdgcn_s_setprio(0);
    GBAR();
    rd_a<1>(afr, Asc, aB0, aB1);
    STG(d + 2, 0);
    GBAR(); WLGKM0();
    __builtin_amdgcn_s_setprio(1); mm16<1>(acc, afr, bfr); __builtin_amdgcn_s_setprio(0);
    GBAR();
    rd_a<2>(afr, Asc, aB0, aB1);
    STG(d + 2, 1);
    GBAR(); WLGKM0();
    __builtin_amdgcn_s_setprio(1); mm16<2>(acc, afr, bfr); __builtin_amdgcn_s_setprio(0);
    GBAR();
    rd_a<3>(afr, Asc, aB0, aB1);
    GBAR(); WLGKM0();
    __builtin_amdgcn_s_setprio(1); mm16<3>(acc, afr, bfr); __builtin_amdgcn_s_setprio(0);
    if (t == iters - 1) { WVM0(); } else { WVM4(); }
    GBAR();
    rd_b(bfr, Bsc + 32768, bB0, bB1);
    rd_a<0>(afr, Asc + 32768, aB0, aB1);
    STG(d + 2, 2);
    GBAR(); WLGKM0();
    __builtin_amdgcn_s_setprio(1); mm16<0>(acc, afr, bfr); __builtin_amdgcn_s_setprio(0);
    GBAR();
    rd_a<1>(afr, Asc + 32768, aB0, aB1);
    STG(d + 2, 3);
    GBAR(); WLGKM0();
    __builtin_amdgcn_s_setprio(1); mm16<1>(acc, afr, bfr); __builtin_amdgcn_s_setprio(0);
    GBAR();
    rd_a<2>(afr, Asc + 32768, aB0, aB1);
    STG(d + 3, 0);
    GBAR(); WLGKM0();
    __builtin_amdgcn_s_setprio(1); mm16<2>(acc, afr, bfr); __builtin_amdgcn_s_setprio(0);
    GBAR();
    rd_a<3>(afr, Asc + 32768, aB0, aB1);
    STG(d + 3, 1);
    GBAR(); WLGKM0();
    __builtin_amdgcn_s_setprio(1); mm16<3>(acc, afr, bfr); __builtin_amdgcn_s_setprio(0);
    WVM4();
    GBAR();
  }

  const int cc = lane & 15;
  const int jb = (lane >> 4) << 2;

  if (NTB) {
    float* lbuf = (float*)lds;
#pragma unroll
    for (int h = 0; h < 2; ++h) {
      if (h) GBAR();
#pragma unroll
      for (int mi4 = 0; mi4 < 4; ++mi4) {
        const int lr = wr * 64 + mi4 * 16 + cc;
#pragma unroll
        for (int ni = 0; ni < 4; ++ni) {
          const int colb = (wc * 64 + ni * 16 + jb) * 4;
          f32x4 v = acc[h * 4 + mi4][ni];
          if (BIAS) v += *(const f32x4*)(bias + n0 + wc * 64 + ni * 16 + jb);
          if (ACT == 1) {
#pragma unroll
            for (int j = 0; j < 4; ++j) v[j] = gelu_f(v[j]);
          }
          *(f32x4*)((char*)lbuf + lr * 1024 + (colb ^ ((lr & 7) << 4))) = v;
        }
      }
      GBAR();
#pragma unroll
      for (int r = 0; r < 16; ++r) {
        const int lr = w * 16 + r;
        const int grow = m0 + h * 64 + lr + ((lr >> 6) << 6);
        const int cb = (lane * 16) ^ ((lr & 7) << 4);
        f32x4 v = *(const f32x4*)((const char*)lbuf + lr * 1024 + cb);
        __builtin_nontemporal_store(
            v, (f32x4*)((char*)((float*)Cout + (size_t)grow * N + n0) + lane * 16));
      }
    }
    return;
  }

  const int orow0 = m0 + wr * 128;
  const int ocol0 = n0 + wc * 64;
#pragma unroll
  for (int mi = 0; mi < 8; ++mi) {
    const int row = orow0 + mi * 16 + cc;
#pragma unroll
    for (int ni = 0; ni < 4; ++ni) {
      const int col = ocol0 + ni * 16 + jb;
      f32x4 v = acc[mi][ni];
      if (BIAS) v += *(const f32x4*)(bias + col);
      if (ACT == 1) {
#pragma unroll
        for (int j = 0; j < 4; ++j) v[j] = gelu_f(v[j]);
      }
      if (OUTBF) {
        u16x4 r;
#pragma unroll
        for (int j = 0; j < 4; ++j) r[j] = f2bf(v[j]);
        *(u16x4*)((u16*)Cout + (size_t)row * N + col) = r;
      } else {
        *(f32x4*)((float*)Cout + (size_t)row * N + col) = v;
      }
    }
  }
}

// =============== 128x128 8-phase MFMA GEMM (layer GEMMs) ===================
template<int PH>
__device__ __forceinline__ void rd_a2(bf16x8 (&afr)[2][2], const char* base,
                                      int aB0, int aB1) {
  afr[0][0] = ldsrd(base + aB0 + PH * 4096);
  afr[0][1] = ldsrd(base + aB1 + PH * 4096);
  afr[1][0] = ldsrd(base + aB0 + PH * 4096 + 2048);
  afr[1][1] = ldsrd(base + aB1 + PH * 4096 + 2048);
}

__device__ __forceinline__ void rd_b2(bf16x8 (&bfr)[2][2], const char* base,
                                      int bB0, int bB1) {
#pragma unroll
  for (int ni = 0; ni < 2; ++ni) {
    bfr[ni][0] = ldsrd(base + bB0 + ni * 2048);
    bfr[ni][1] = ldsrd(base + bB1 + ni * 2048);
  }
}

template<int PH>
__device__ __forceinline__ void mm8(f32x4 (&acc)[4][2], bf16x8 (&afr)[2][2],
                                    bf16x8 (&bfr)[2][2]) {
#pragma unroll
  for (int ni = 0; ni < 2; ++ni) {
    acc[PH*2+0][ni] = __builtin_amdgcn_mfma_f32_16x16x32_bf16(bfr[ni][0], afr[0][0], acc[PH*2+0][ni], 0, 0, 0);
    acc[PH*2+0][ni] = __builtin_amdgcn_mfma_f32_16x16x32_bf16(bfr[ni][1], afr[0][1], acc[PH*2+0][ni], 0, 0, 0);
    acc[PH*2+1][ni] = __builtin_amdgcn_mfma_f32_16x16x32_bf16(bfr[ni][0], afr[1][0], acc[PH*2+1][ni], 0, 0, 0);
    acc[PH*2+1][ni] = __builtin_amdgcn_mfma_f32_16x16x32_bf16(bfr[ni][1], afr[1][1], acc[PH*2+1][ni], 0, 0, 0);
  }
}

template<int ACT, bool BIAS, bool RES, bool OUTBF>
__global__ __launch_bounds__(512, 4) void gemm128_8ph(
    const bf16_t* __restrict__ A, const bf16_t* __restrict__ W,
    const float* __restrict__ bias, const float* __restrict__ res,
    void* __restrict__ Cout, int M, int N, int K) {
  __shared__ char lds[65536];
  char* Asc = lds;
  char* Bsc = lds + 32768;

  const int tid  = threadIdx.x;
  const int lane = tid & 63;
  const int w    = tid >> 6;
  const int wr   = w >> 2, wc = w & 3;

  const int nwg = gridDim.x * gridDim.y;
  const int bid = blockIdx.y * gridDim.x + blockIdx.x;
  const int swz = (bid & 7) * (nwg >> 3) + (bid >> 3);
  const int m0 = (swz & 31) << 7;
  const int n0 = (swz >> 5) << 7;

  const size_t K2 = (size_t)K * 2;
  const int KT = K >> 6;

  const int qsrc = (((tid & 7) ^ ((tid >> 3) & 7)) << 4);
  const char* srcA = (const char*)A + (size_t)(m0 + (tid >> 3)) * K2 + qsrc;
  const char* srcB = (const char*)W + (size_t)(n0 + (tid >> 3)) * K2 + qsrc;
  char* dstA = Asc + (tid & 448) * 16;
  char* dstB = Bsc + (tid & 448) * 16;

  auto STG = [&](int kt, int part) {
    if (kt >= KT) return;
    const int h = part & 1;
    const size_t so = (size_t)(h * 64) * K2 + (size_t)kt * 128;
    const int dofs = ((kt & 1) << 14) + (h << 13);
    if (part >= 2) gload16(srcA + so, dstA + dofs);
    else           gload16(srcB + so, dstB + dofs);
  };

  const int rr = lane & 15;
  const int q0 = (((lane >> 4) ^ (lane & 7)) << 4);
  const int aB0 = ((wr << 6) + rr) * 128 + q0;
  const int aB1 = ((wr << 6) + rr) * 128 + (q0 ^ 64);
  const int bB0 = ((wc << 5) + rr) * 128 + q0;
  const int bB1 = ((wc << 5) + rr) * 128 + (q0 ^ 64);

  bf16x8 bfr[2][2];
  bf16x8 afr[2][2];
  f32x4 acc[4][2] = {};

  STG(0, 0); STG(0, 1); STG(0, 2); STG(0, 3);
  STG(1, 0); STG(1, 1);
  WVM2();
  GBAR();

  const int iters = KT >> 1;
  for (int t = 0; t < iters; ++t) {
    const int d = t << 1;
    rd_b2(bfr, Bsc, bB0, bB1);
    rd_a2<0>(afr, Asc, aB0, aB1);
    STG(d + 1, 2); STG(d + 1, 3);
    GBAR(); WLGKM0();
    __builtin_amdgcn_s_setprio(1); mm8<0>(acc, afr, bfr); __builtin_amdgcn_s_setprio(0);
    GBAR();
    rd_a2<1>(afr, Asc, aB0, aB1);
    STG(d + 2, 0); STG(d + 2, 1);
    GBAR(); WLGKM0();
    __builtin_amdgcn_s_setprio(1); mm8<1>(acc, afr, bfr); __builtin_amdgcn_s_setprio(0);
    if (t == iters - 1) { WVM0(); } else { WVM2(); }
    GBAR();
    rd_b2(bfr, Bsc + 16384, bB0, bB1);
    rd_a2<0>(afr, Asc + 16384, aB0, aB1);
    STG(d + 2, 2); STG(d + 2, 3);
    GBAR(); WLGKM0();
    __builtin_amdgcn_s_setprio(1); mm8<0>(acc, afr, bfr); __builtin_amdgcn_s_setprio(0);
    GBAR();
    rd_a2<1>(afr, Asc + 16384, aB0, aB1);
    STG(d + 3, 0); STG(d + 3, 1);
    GBAR(); WLGKM0();
    __builtin_amdgcn_s_setprio(1); mm8<1>(acc, afr, bfr); __builtin_amdgcn_s_setprio(0);
    WVM2();
    GBAR();
  }

  const int cc = lane & 15;
  const int jb = (lane >> 4) << 2;
  const int orow0 = m0 + wr * 64;
  const int ocol0 = n0 + wc * 32;
#pragma unroll
  for (int mi = 0; mi < 4; ++mi) {
    const int row = orow0 + mi * 16 + cc;
#pragma unroll
    for (int ni = 0; ni < 2; ++ni) {
      const int col = ocol0 + ni * 16 + jb;
      f32x4 v = acc[mi][ni];
      if (BIAS) v += *(const f32x4*)(bias + col);
      if (ACT == 1) {
#pragma unroll
        for (int j = 0; j < 4; ++j) v[j] = gelu_f(v[j]);
      }
      if (RES) v += *(const f32x4*)(res + (size_t)row * N + col);
      if (OUTBF) {
        u16x4 r;
#pragma unroll
        for (int j = 0; j < 4; ++j) r[j] = f2bf(v[j]);
        *(u16x4*)((u16*)Cout + (size_t)row * N + col) = r;
      } else {
        *(f32x4*)((float*)Cout + (size_t)row * N + col) = v;
      }
    }
  }
}

// ----------------- MFMA flash attention (QBLK=128, KVBLK=128) --------------
__global__ __launch_bounds__(512) void attn_mfma_kernel(
    const u16* __restrict__ qkv, u16* __restrict__ out) {
  const int bh  = blockIdx.y;
  const int b = bh >> 4, h = bh & 15;
  const int tid = threadIdx.x;
  const int lane = tid & 63, w = tid >> 6;

  __shared__ u16 Ks[128][72];
  __shared__ u16 Vt[64][136];
  __shared__ u16 Ps[8][16][136];

  const size_t rowstr = 3 * DMODEL;
  const u16* base = qkv + (size_t)b * TSEQ * rowstr;

  const int fr = lane & 15;
  const int fk = (lane >> 4) * 8;

  bf16x8 onesf;
#pragma unroll
  for (int i = 0; i < 8; ++i) ((u16*)&onesf)[i] = 0x3F80;  // bf16 1.0

  const int skr = tid >> 2;
  const int skc = (tid & 3) * 16;
  const int vk0 = (tid & 63) * 2;
  const int vd0 = (tid >> 6) * 8;

#pragma unroll 1
  for (int half = 0; half < 2; ++half) {
    const int st  = half ? (15 - (int)blockIdx.x) : (int)blockIdx.x;
    const int qb0 = st * 128;
    const int qminw = qb0 + w * 16;
    const int qrow = qminw + fr;

    u16x8 q0r = *(const u16x8*)(base + (size_t)qrow * rowstr + h * HDIM + fk);
    u16x8 q1r = *(const u16x8*)(base + (size_t)qrow * rowstr + h * HDIM + fk + 32);
    bf16x8 qf0, qf1;
#pragma unroll
    for (int i = 0; i < 8; ++i) {
      ((u16*)&qf0)[i] = f2bf(__uint_as_float((unsigned)q0r[i] << 16) * 0.18033688011112042f);
      ((u16*)&qf1)[i] = f2bf(__uint_as_float((unsigned)q1r[i] << 16) * 0.18033688011112042f);
    }

    f32x4 o[4] = {};
    f32x4 ls = {};

    u16x8 k0, k1, va0, vb0;
    {
      const u16* kr = base + (size_t)skr * rowstr + DMODEL + h * HDIM + skc;
      k0 = *(const u16x8*)kr;  k1 = *(const u16x8*)(kr + 8);
      const u16* vr = base + (size_t)vk0 * rowstr + 2 * DMODEL + h * HDIM + vd0;
      va0 = *(const u16x8*)vr; vb0 = *(const u16x8*)(vr + rowstr);
    }

    for (int s0 = 0; s0 < qb0 + 128; s0 += 128) {
      __syncthreads();
      *(u16x8*)&Ks[skr][skc]     = k0;
      *(u16x8*)&Ks[skr][skc + 8] = k1;
#pragma unroll
      for (int i = 0; i < 8; ++i)
        *(unsigned*)&Vt[vd0 + i][vk0] = (unsigned)va0[i] | ((unsigned)vb0[i] << 16);
      __syncthreads();

      if (s0 + 128 < qb0 + 128) {
        const u16* kr = base + (size_t)(s0 + 128 + skr) * rowstr + DMODEL + h * HDIM + skc;
        k0 = *(const u16x8*)kr;  k1 = *(const u16x8*)(kr + 8);
        const u16* vr = base + (size_t)(s0 + 128 + vk0) * rowstr + 2 * DMODEL + h * HDIM + vd0;
        va0 = *(const u16x8*)vr; vb0 = *(const u16x8*)(vr + rowstr);
      } else if (half == 0) {
        const u16* kr = base + (size_t)skr * rowstr + DMODEL + h * HDIM + skc;
        k0 = *(const u16x8*)kr;  k1 = *(const u16x8*)(kr + 8);
        const u16* vr = base + (size_t)vk0 * rowstr + 2 * DMODEL + h * HDIM + vd0;
        va0 = *(const u16x8*)vr; vb0 = *(const u16x8*)(vr + rowstr);
      }

      f32x4 s[8];
      __builtin_amdgcn_s_setprio(1);
#pragma unroll
      for (int ni = 0; ni < 8; ++ni) {
        f32x4 t = {};
        bf16x8 kf0 = *(const bf16x8*)&Ks[ni * 16 + fr][fk];
        bf16x8 kf1 = *(const bf16x8*)&Ks[ni * 16 + fr][fk + 32];
        t = __builtin_amdgcn_mfma_f32_16x16x32_bf16(qf0, kf0, t, 0, 0, 0);
        t = __builtin_amdgcn_mfma_f32_16x16x32_bf16(qf1, kf1, t, 0, 0, 0);
        s[ni] = t;
      }
      __builtin_amdgcn_s_setprio(0);

      if (s0 == qb0) {
        const int q0_ = qminw + (lane >> 4) * 4;
#pragma unroll
        for (int ni = 0; ni < 8; ++ni)
#pragma unroll
          for (int j = 0; j < 4; ++j)
            if (s0 + ni * 16 + fr > q0_ + j) s[ni][j] = -3e38f;
      }

#pragma unroll
      for (int ni = 0; ni < 8; ++ni)
#pragma unroll
        for (int j = 0; j < 4; ++j) {
          float pv = exp2_raw(fminf(s[ni][j], 115.41560327f) - 11.541560327111707f);
          Ps[w][(lane >> 4) * 4 + j][ni * 16 + fr] = f2bf(pv);
        }
      WLGKM0();

      bf16x8 pf0 = *(const bf16x8*)&Ps[w][fr][fk];
      bf16x8 pf1 = *(const bf16x8*)&Ps[w][fr][fk + 32];
      bf16x8 pf2 = *(const bf16x8*)&Ps[w][fr][64 + fk];
      bf16x8 pf3 = *(const bf16x8*)&Ps[w][fr][96 + fk];
      __builtin_amdgcn_s_setprio(1);
#pragma unroll
      for (int ni = 0; ni < 4; ++ni) {
        bf16x8 vf0 = *(const bf16x8*)&Vt[ni * 16 + fr][fk];
        bf16x8 vf1 = *(const bf16x8*)&Vt[ni * 16 + fr][fk + 32];
        bf16x8 vf2 = *(const bf16x8*)&Vt[ni * 16 + fr][64 + fk];
        bf16x8 vf3 = *(const bf16x8*)&Vt[ni * 16 + fr][96 + fk];
        o[ni] = __builtin_amdgcn_mfma_f32_16x16x32_bf16(pf0, vf0, o[ni], 0, 0, 0);
        o[ni] = __builtin_amdgcn_mfma_f32_16x16x32_bf16(pf1, vf1, o[ni], 0, 0, 0);
        o[ni] = __builtin_amdgcn_mfma_f32_16x16x32_bf16(pf2, vf2, o[ni], 0, 0, 0);
        o[ni] = __builtin_amdgcn_mfma_f32_16x16x32_bf16(pf3, vf3, o[ni], 0, 0, 0);
      }
      ls = __builtin_amdgcn_mfma_f32_16x16x32_bf16(pf0, onesf, ls, 0, 0, 0);
      ls = __builtin_amdgcn_mfma_f32_16x16x32_bf16(pf1, onesf, ls, 0, 0, 0);
      ls = __builtin_amdgcn_mfma_f32_16x16x32_bf16(pf2, onesf, ls, 0, 0, 0);
      ls = __builtin_amdgcn_mfma_f32_16x16x32_bf16(pf3, onesf, ls, 0, 0, 0);
      __builtin_amdgcn_s_setprio(0);
    }

#pragma unroll
    for (int j = 0; j < 4; ++j) {
      float inv = 1.0f / ls[j];
      int q = qminw + (lane >> 4) * 4 + j;
      u16* op = out + ((size_t)(b * TSEQ) + q) * DMODEL + h * HDIM + fr;
#pragma unroll
      for (int ni = 0; ni < 4; ++ni)
        op[ni * 16] = f2bf(o[ni][j] * inv);
    }
  }
}

// ------------------------------ launcher ----------------------------------
extern "C" void kernel_launch(void* const* d_in, const int* in_sizes, int n_in,
                              void* d_out, int out_size, void* d_ws, size_t ws_size,
                              hipStream_t stream) {
  const int*   ids    = (const int*)d_in[0];
  const float* emb    = (const float*)d_in[1];
  const float* pos    = (const float*)d_in[2];
  const float* ln1_g  = (const float*)d_in[3];
  const float* ln1_b  = (const float*)d_in[4];
  const float* ln2_g  = (const float*)d_in[5];
  const float* ln2_b  = (const float*)d_in[6];
  const float* qkv_w  = (const float*)d_in[7];
  const float* out_w  = (const float*)d_in[8];
  const float* mlp_w1 = (const float*)d_in[9];
  const float* mlp_b1 = (const float*)d_in[10];
  const float* mlp_w2 = (const float*)d_in[11];
  const float* mlp_b2 = (const float*)d_in[12];
  const float* lnf_g  = (const float*)d_in[13];
  const float* lnf_b  = (const float*)d_in[14];
  float* outp = (float*)d_out;

  const int M = BATCH * TSEQ;                         // 4096
  char* p = (char*)d_ws;
  float* x    = (float*)p;  p += (size_t)M * DMODEL * 4;
  u16*   yb   = (u16*)p;    p += (size_t)M * DMODEL * 2;
  u16*   qkvb = (u16*)p;    p += (size_t)M * 3 * DMODEL * 2;
  u16*   mid  = (u16*)p;    p += (size_t)M * DFFN * 2;
  u16*   wq   = (u16*)p;    p += (size_t)3 * DMODEL * DMODEL * 2;
  u16*   wo   = (u16*)p;    p += (size_t)DMODEL * DMODEL * 2;
  u16*   w1   = (u16*)p;    p += (size_t)DFFN * DMODEL * 2;
  u16*   w2   = (u16*)p;    p += (size_t)DMODEL * DFFN * 2;
  u16*   embb = qkvb;  // final stage: reuse qkvb+mid+wq/wo (all dead)

  embed_kernel<<<M, 256, 0, stream>>>(ids, emb, pos, x);

  for (int l = 0; l < NLAYER; ++l) {
    prep_kernel<<<10240, 256, 0, stream>>>(
        qkv_w  + (size_t)l * 3 * DMODEL * DMODEL,
        out_w  + (size_t)l * DMODEL * DMODEL,
        mlp_w1 + (size_t)l * DFFN * DMODEL,
        mlp_w2 + (size_t)l * DMODEL * DFFN,
        wq, wo, w1, w2,
        x, ln1_g + l * DMODEL, ln1_b + l * DMODEL, yb);

    gemm128_8ph<0, false, false, true><<<dim3(3 * DMODEL / 128, M / 128), 512, 0, stream>>>(
        (const bf16_t*)yb, (const bf16_t*)wq, nullptr, nullptr, qkvb, M, 3 * DMODEL, DMODEL);
    attn_mfma_kernel<<<dim3(8, BATCH * NHEAD), 512, 0, stream>>>(qkvb, yb);
    gemm128_8ph<0, false, true, false><<<dim3(DMODEL / 128, M / 128), 512, 0, stream>>>(
        (const bf16_t*)yb, (const bf16_t*)wo, nullptr, x, x, M, DMODEL, DMODEL);
    ln_kernel<<<M, 256, 0, stream>>>(x, ln2_g + l * DMODEL, ln2_b + l * DMODEL, yb);
    gemm128_8ph<1, true, false, true><<<dim3(DFFN / 128, M / 128), 512, 0, stream>>>(
        (const bf16_t*)yb, (const bf16_t*)w1, mlp_b1 + (size_t)l * DFFN, nullptr, mid,
        M, DFFN, DMODEL);
    gemm128_8ph<0, true, true, false><<<dim3(DMODEL / 128, M / 128), 512, 0, stream>>>(
        (const bf16_t*)mid, (const bf16_t*)w2, mlp_b2 + (size_t)l * DMODEL, x, x,
        M, DMODEL, DFFN);
  }

  finprep_kernel<<<20096, 256, 0, stream>>>(x, lnf_g, lnf_b, yb, emb, embb);
  gemm_mfma256<0, false, false, true><<<dim3(NVOCAB / 256, M / 256), 512, 0, stream>>>(
      (const bf16_t*)yb, (const bf16_t*)embb, nullptr, outp, M, NVOCAB, DMODEL);
}